// Round 1
// baseline (99.384 us; speedup 1.0000x reference)
//
#include <hip/hip_runtime.h>

// Phase 1: per-node dot products s[n] = x[n]·att[0:128], t[n] = x[n]·att[128:256]
// One wave handles 2 nodes (256 contiguous floats = 64 lanes × float4).
__global__ __launch_bounds__(256) void node_dots_kernel(
    const float* __restrict__ x, const float* __restrict__ att,
    float* __restrict__ s, float* __restrict__ t, int n_pairs) {
  int gtid = blockIdx.x * blockDim.x + threadIdx.x;
  int pair = gtid >> 6;          // wave index
  int lane = threadIdx.x & 63;
  if (pair >= n_pairs) return;

  // 64 float4 = 256 floats = rows for nodes 2*pair and 2*pair+1 (contiguous)
  const float4* xr = (const float4*)x + (size_t)pair * 64 + lane;
  float4 v = *xr;

  int wl = lane & 31;            // position within half-wave (one node = 32 lanes)
  const float4* a4 = (const float4*)att;
  float4 ws = a4[wl];            // att[0:128]  (w_src)
  float4 wt = a4[32 + wl];       // att[128:256] (w_tgt)

  float ps = v.x * ws.x + v.y * ws.y + v.z * ws.z + v.w * ws.w;
  float pt = v.x * wt.x + v.y * wt.y + v.z * wt.z + v.w * wt.w;

  // Half-wave (32-lane) tree reduction. Lanes 0 and 32 end with the two sums.
  #pragma unroll
  for (int off = 16; off; off >>= 1) {
    ps += __shfl_down(ps, off);
    pt += __shfl_down(pt, off);
  }
  if (wl == 0) {
    int n = 2 * pair + (lane >> 5);
    s[n] = ps;
    t[n] = pt;
  }
}

// Phase 2: out[e] = relu(s[src[e]] + t[tgt[e]])
// s/t total 800 KB -> resident in L2; index reads + output write are coalesced.
__global__ __launch_bounds__(256) void edge_signal_kernel(
    const int* __restrict__ src, const int* __restrict__ tgt,
    const float* __restrict__ s, const float* __restrict__ t,
    float* __restrict__ out, int n_edges) {
  int i = blockIdx.x * blockDim.x + threadIdx.x;
  if (i >= n_edges) return;
  float v = s[src[i]] + t[tgt[i]];
  out[i] = v > 0.0f ? v : 0.0f;
}

extern "C" void kernel_launch(void* const* d_in, const int* in_sizes, int n_in,
                              void* d_out, int out_size, void* d_ws, size_t ws_size,
                              hipStream_t stream) {
  const float* x_0  = (const float*)d_in[0];
  const int*   src  = (const int*)d_in[1];
  const int*   tgt  = (const int*)d_in[2];
  const float* att  = (const float*)d_in[3];
  float* out = (float*)d_out;

  const int C = 128;
  int n_nodes = in_sizes[0] / C;   // 100000
  int n_edges = in_sizes[1];       // 800000

  float* s = (float*)d_ws;         // n_nodes floats
  float* t = s + n_nodes;          // n_nodes floats

  int n_pairs = (n_nodes + 1) / 2; // 2 nodes per wave
  int waves_per_block = 256 / 64;
  int grid1 = (n_pairs + waves_per_block - 1) / waves_per_block;
  node_dots_kernel<<<grid1, 256, 0, stream>>>(x_0, att, s, t, n_pairs);

  int grid2 = (n_edges + 255) / 256;
  edge_signal_kernel<<<grid2, 256, 0, stream>>>(src, tgt, s, t, out, n_edges);
}